// Round 8
// baseline (245.333 us; speedup 1.0000x reference)
//
#include <hip/hip_runtime.h>

// Factored single-row attention (reference returns out[:, -1, :] only).
// ws layout (floats): M2p [0,65536) packed [k4][e][4]; Wvp [65536,131072)
// packed [d4][e][4]; v0 @131072; c @131328; w1 @131584; w2 @131840;
// dconst {sum(bk), bq.bk, sum(bq)} (3 dbl) @132096; Sq (2048 dbl) @132608;
// Qbk (2048 dbl) @136704; u/y (2048x256 f32, u overwritten by y) @140800.
//   M2[f][d] = sum_e Wq[e][f] Wk[e][d]  (u = td*(x49@M2) + v0)
//   v0[d] = sum_e bq[e] Wk[e][d];  c[d] = sum_e Wk[e][d]
//   w1[f] = sum_e bk[e] Wq[e][f];  w2[f] = sum_e Wq[e][f]
// Score paths (identical to passing rounds 1-7):
//   q-kept & s-kept : (td_s*(x_s.u) + q.bk)/16
//   q-kept & s-mask : NEG*sum(q)/16
//   q-mask & s-kept : NEG*(td_s*(x_s.c) + sum(bk))/16   both: 256e10/16
// Round-8: round-7's fused kernel was latency-bound (occupancy 10%, VALU
// 25%): 4 waves/CU cap + serial online-softmax chain. Split phases so attn
// gets 2048 waves (8/CU); attn rewritten as TWO INDEPENDENT PASSES:
// pass1 = 50 independent raw dots (td factored out of the dot), parity
// butterfly reduce (2 rows per 6-shfl chain; row 2i -> even lanes, 2i+1 ->
// odd), fp64 scores/exp halved per lane, max/sum via 1 cross-parity shfl,
// pass2 = re-stream L2-hot rows with broadcast weights. No loop-carried
// dependency anywhere. u_gemm/o_gemm/precomp verbatim from round 6.

namespace {
constexpr int kB = 2048;
constexpr int kT = 50;
constexpr int kD = 256;
constexpr int kThr = 256;
constexpr double kNeg = -100000.0;
constexpr int oM2 = 0;
constexpr int oWvp = 65536;
constexpr int oV0 = 131072;
constexpr int oC = 131328;
constexpr int oW1 = 131584;
constexpr int oW2 = 131840;
constexpr int oDbl = 132096;  // 3 doubles
constexpr int oSq = 132608;   // 2048 doubles
constexpr int oQbk = 136704;  // 2048 doubles
constexpr int oU = 140800;    // 2048*256 floats (u, then y)
}  // namespace

// ---------------- precomp: VERBATIM from rounds 5-7 (proven) --------------
__global__ __launch_bounds__(kThr) void precomp(
    const float* __restrict__ Wq, const float* __restrict__ bq,
    const float* __restrict__ Wk, const float* __restrict__ bk,
    const float* __restrict__ Wv, float* __restrict__ ws) {
  const int t = threadIdx.x;
  const int wave = t >> 6;
  const int lane = t & 63;
  const int blk = blockIdx.x;
  __shared__ float coefL[kD];
  __shared__ double red[3][4];

  if (blk < 256) {
    const int a = blk;
    coefL[t] = Wq[(size_t)t * kD + a];
    __syncthreads();
    const float* kcol = Wk + t;
    float pre[8];
#pragma unroll
    for (int k = 0; k < 8; ++k) pre[k] = kcol[(size_t)k * kD];
    float acc = 0.f;
    for (int j0 = 0; j0 < kD; j0 += 8) {
      float cur[8];
#pragma unroll
      for (int k = 0; k < 8; ++k) cur[k] = pre[k];
      const int nx = (j0 + 8 < kD) ? (j0 + 8) : 0;
#pragma unroll
      for (int k = 0; k < 8; ++k) pre[k] = kcol[(size_t)(nx + k) * kD];
#pragma unroll
      for (int k = 0; k < 8; ++k) acc += coefL[j0 + k] * cur[k];
    }
    ws[oM2 + (a >> 2) * 1024 + 4 * t + (a & 3)] = acc;
  } else if (blk < 258) {
    const float* W = (blk == 256) ? Wk : Wq;
    const float* coef = (blk == 256) ? bq : bk;
    coefL[t] = coef[t];
    __syncthreads();
    const float* col = W + t;
    float pre[8];
#pragma unroll
    for (int k = 0; k < 8; ++k) pre[k] = col[(size_t)k * kD];
    double a0 = 0.0, a1 = 0.0;
    for (int j0 = 0; j0 < kD; j0 += 8) {
      float cur[8];
#pragma unroll
      for (int k = 0; k < 8; ++k) cur[k] = pre[k];
      const int nx = (j0 + 8 < kD) ? (j0 + 8) : 0;
#pragma unroll
      for (int k = 0; k < 8; ++k) pre[k] = col[(size_t)(nx + k) * kD];
#pragma unroll
      for (int k = 0; k < 8; ++k) {
        const double w = (double)cur[k];
        a0 += (double)coefL[j0 + k] * w;
        a1 += w;
      }
    }
    if (blk == 256) {
      ws[oV0 + t] = (float)a0;
      ws[oC + t] = (float)a1;
    } else {
      ws[oW1 + t] = (float)a0;
      ws[oW2 + t] = (float)a1;
      double p0 = (double)bk[t];
      double p1 = (double)bq[t] * (double)bk[t];
      double p2 = (double)bq[t];
#pragma unroll
      for (int off = 32; off; off >>= 1) {
        p0 += __shfl_xor(p0, off);
        p1 += __shfl_xor(p1, off);
        p2 += __shfl_xor(p2, off);
      }
      if (lane == 0) {
        red[0][wave] = p0;
        red[1][wave] = p1;
        red[2][wave] = p2;
      }
      __syncthreads();
      if (t == 0) {
        double* dcw = (double*)(ws + oDbl);
        dcw[0] = red[0][0] + red[0][1] + red[0][2] + red[0][3];
        dcw[1] = red[1][0] + red[1][1] + red[1][2] + red[1][3];
        dcw[2] = red[2][0] + red[2][1] + red[2][2] + red[2][3];
      }
    }
  } else {
    const int d4b = (blk - 258) * 4;
    float4 in[4];
#pragma unroll
    for (int k = 0; k < 4; ++k)
      in[k] = *(const float4*)(Wv + (size_t)t * kD + 4 * (d4b + k));
    float4* Wvp = (float4*)(ws + oWvp);
#pragma unroll
    for (int k = 0; k < 4; ++k) Wvp[(size_t)(d4b + k) * kD + t] = in[k];
  }
}

// ---------------- u_gemm: VERBATIM from round 6 (proven) ------------------
__global__ __launch_bounds__(kThr) void u_gemm(const float* __restrict__ x,
                                               const float* __restrict__ td,
                                               float* __restrict__ ws) {
  const int t = threadIdx.x;
  const int wave = t >> 6;
  const int lane = t & 63;
  const int b0 = blockIdx.x * 4;
  const double* dc = (const double*)(ws + oDbl);

  {
    const int b = b0 + wave;
    const float4 xv =
        ((const float4*)(x + ((size_t)b * kT + kT - 1) * kD))[lane];
    const float4 a1 = ((const float4*)(ws + oW1))[lane];
    const float4 a2 = ((const float4*)(ws + oW2))[lane];
    double s1 = (double)xv.x * a1.x + (double)xv.y * a1.y +
                (double)xv.z * a1.z + (double)xv.w * a1.w;
    double s2 = (double)xv.x * a2.x + (double)xv.y * a2.y +
                (double)xv.z * a2.z + (double)xv.w * a2.w;
#pragma unroll
    for (int off = 32; off; off >>= 1) {
      s1 += __shfl_xor(s1, off);
      s2 += __shfl_xor(s2, off);
    }
    if (lane == 0) {
      const double tdd = (double)td[(size_t)b * kT + kT - 1];
      ((double*)(ws + oQbk))[b] = tdd * s1 + dc[1];
      ((double*)(ws + oSq))[b] = tdd * s2 + dc[2];
    }
  }

  const float4* M2v = (const float4*)(ws + oM2);
  const float4* r0 = (const float4*)(x + ((size_t)(b0 + 0) * kT + kT - 1) * kD);
  const float4* r1 = (const float4*)(x + ((size_t)(b0 + 1) * kT + kT - 1) * kD);
  const float4* r2 = (const float4*)(x + ((size_t)(b0 + 2) * kT + kT - 1) * kD);
  const float4* r3 = (const float4*)(x + ((size_t)(b0 + 3) * kT + kT - 1) * kD);
  const float td0 = td[(size_t)(b0 + 0) * kT + kT - 1];
  const float td1 = td[(size_t)(b0 + 1) * kT + kT - 1];
  const float td2 = td[(size_t)(b0 + 2) * kT + kT - 1];
  const float td3 = td[(size_t)(b0 + 3) * kT + kT - 1];

  float4 pre[8];
#pragma unroll
  for (int k = 0; k < 8; ++k) pre[k] = M2v[(size_t)k * kD + t];
  float acc0 = 0.f, acc1 = 0.f, acc2 = 0.f, acc3 = 0.f;
  for (int j0 = 0; j0 < 64; j0 += 8) {
    float4 cur[8];
#pragma unroll
    for (int k = 0; k < 8; ++k) cur[k] = pre[k];
    const int nx = (j0 + 8 < 64) ? (j0 + 8) : 0;
#pragma unroll
    for (int k = 0; k < 8; ++k) pre[k] = M2v[(size_t)(nx + k) * kD + t];
#pragma unroll
    for (int k = 0; k < 8; ++k) {
      const float4 m = cur[k];
      const float4 x0 = r0[j0 + k];
      const float4 x1 = r1[j0 + k];
      const float4 x2 = r2[j0 + k];
      const float4 x3 = r3[j0 + k];
      acc0 += x0.x * m.x + x0.y * m.y + x0.z * m.z + x0.w * m.w;
      acc1 += x1.x * m.x + x1.y * m.y + x1.z * m.z + x1.w * m.w;
      acc2 += x2.x * m.x + x2.y * m.y + x2.z * m.z + x2.w * m.w;
      acc3 += x3.x * m.x + x3.y * m.y + x3.z * m.z + x3.w * m.w;
    }
  }
  const float v0t = ws[oV0 + t];
  ws[oU + (size_t)(b0 + 0) * kD + t] = td0 * acc0 + v0t;
  ws[oU + (size_t)(b0 + 1) * kD + t] = td1 * acc1 + v0t;
  ws[oU + (size_t)(b0 + 2) * kD + t] = td2 * acc2 + v0t;
  ws[oU + (size_t)(b0 + 3) * kD + t] = td3 * acc3 + v0t;
}

// ------- attn: 1 wave/batch, two independent passes, parity reduce -------
__global__ __launch_bounds__(64, 2) void attn(const float* __restrict__ x,
                                              const int* __restrict__ mask,
                                              const float* __restrict__ td,
                                              float* __restrict__ ws) {
  const int lane = threadIdx.x;
  const int b = blockIdx.x;
  const int par = lane & 1;

  // mask row -> wave-uniform 64-bit word (bit s = keep row s)
  const int ml = (lane < kT) ? mask[(size_t)b * kT + lane] : 0;
  const unsigned long long mm = __ballot(ml != 0);
  const int mqg = (int)((mm >> (kT - 1)) & 1ull);

  const float4 u4 = ((const float4*)(ws + oU))[(size_t)b * 64 + lane];
  const float4 c4 = ((const float4*)(ws + oC))[lane];
  const float4 v4 = mqg ? u4 : c4;

  const double* dcp = (const double*)(ws + oDbl);
  const double sbkd = dcp[0];
  const double Sq = ((const double*)(ws + oSq))[b];
  const double Qbk = ((const double*)(ws + oQbk))[b];
  const double Cm = kNeg * Sq * 0.0625;
  const double Cbb = 256.0 * 1.0e10 * 0.0625;

  const float4* xrow = (const float4*)(x + (size_t)b * kT * kD);
  const float* tdr = td + (size_t)b * kT;  // uniform -> s_load

  // ---- pass 1: 50 independent raw dots x_s.v4 (td factored out) ----
  float dot[kT];
  {
    float4 PF[8];
#pragma unroll
    for (int i = 0; i < 8; ++i) PF[i] = xrow[i * 64 + lane];
#pragma unroll
    for (int s = 0; s < kT; ++s) {
      const float4 r = PF[s & 7];
      if (s + 8 < kT) PF[s & 7] = xrow[(s + 8) * 64 + lane];
      dot[s] = r.x * v4.x + r.y * v4.y + r.z * v4.z + r.w * v4.w;
    }
  }

  // ---- parity butterfly reduce: R[i] = full sum of row 2i (even lanes)
  //      / row 2i+1 (odd lanes). xor-1 merges the pair, 5 same-parity
  //      steps finish. No loop-carried dependency across i. ----
  float R[kT / 2];
#pragma unroll
  for (int i = 0; i < kT / 2; ++i) {
    const float sA = dot[2 * i], sB = dot[2 * i + 1];
    const float snd = par ? sA : sB;  // send what the partner accumulates
    const float o = __shfl_xor(snd, 1);
    float r = (par ? sB : sA) + o;
    r += __shfl_xor(r, 2);
    r += __shfl_xor(r, 4);
    r += __shfl_xor(r, 8);
    r += __shfl_xor(r, 16);
    r += __shfl_xor(r, 32);
    R[i] = r;
  }

  // ---- fp64 scores for MY parity's 25 rows (row s = 2i+par) ----
  double sc[kT / 2];
#pragma unroll
  for (int i = 0; i < kT / 2; ++i) {
    const float tdA = tdr[2 * i], tdB = tdr[2 * i + 1];
    const double tds = (double)(par ? tdB : tdA);
    const int msA = (int)((mm >> (2 * i)) & 1ull);
    const int msB = (int)((mm >> (2 * i + 1)) & 1ull);
    const int ms = par ? msB : msA;
    const double xd = tds * (double)R[i];
    if (mqg)
      sc[i] = ms ? (xd + Qbk) * 0.0625 : Cm;
    else
      sc[i] = ms ? kNeg * (xd + sbkd) * 0.0625 : Cbb;
  }

  // ---- max / exp / sum: cross-parity via ONE xor-1 shfl each ----
  double mloc = sc[0];
#pragma unroll
  for (int i = 1; i < kT / 2; ++i) mloc = sc[i] > mloc ? sc[i] : mloc;
  const double mo = __shfl_xor(mloc, 1);
  const double m = mloc > mo ? mloc : mo;

  float ef[kT / 2];
  float lloc = 0.f;
#pragma unroll
  for (int i = 0; i < kT / 2; ++i) {
    ef[i] = expf((float)(sc[i] - m));
    lloc += ef[i];
  }
  const float l = lloc + __shfl_xor(lloc, 1);
  const float inv = 1.0f / l;

  // weights (fold td): w_s = e_s * inv * td_s; broadcast both parities
  float wA[kT / 2], wB[kT / 2];
#pragma unroll
  for (int i = 0; i < kT / 2; ++i) {
    const float tdA = tdr[2 * i], tdB = tdr[2 * i + 1];
    const float wp = ef[i] * inv * (par ? tdB : tdA);
    wA[i] = __shfl(wp, 0);  // lane 0 = even parity = row 2i
    wB[i] = __shfl(wp, 1);  // lane 1 = odd parity  = row 2i+1
  }

  // ---- pass 2: y = sum_s w_s * x_s (rows L2-hot from pass 1) ----
  float4 y = {0.f, 0.f, 0.f, 0.f};
  {
    float4 PF[8];
#pragma unroll
    for (int i = 0; i < 8; ++i) PF[i] = xrow[i * 64 + lane];
#pragma unroll
    for (int s = 0; s < kT; ++s) {
      const float4 r = PF[s & 7];
      if (s + 8 < kT) PF[s & 7] = xrow[(s + 8) * 64 + lane];
      const float w = (s & 1) ? wB[s >> 1] : wA[s >> 1];
      y.x += w * r.x;
      y.y += w * r.y;
      y.z += w * r.z;
      y.w += w * r.w;
    }
  }
  ((float4*)(ws + oU))[(size_t)b * 64 + lane] = y;  // overwrite u with y
}

// ---------------- o_gemm: VERBATIM from round 6 (proven) ------------------
__global__ __launch_bounds__(kThr) void o_gemm(const float* __restrict__ bv,
                                               const float* __restrict__ ws,
                                               float* __restrict__ out) {
  const int t = threadIdx.x;
  const int b0 = blockIdx.x * 4;
  const float4* Wvv = (const float4*)(ws + oWvp);
  const float4* y0 = (const float4*)(ws + oU + (size_t)(b0 + 0) * kD);
  const float4* y1 = (const float4*)(ws + oU + (size_t)(b0 + 1) * kD);
  const float4* y2 = (const float4*)(ws + oU + (size_t)(b0 + 2) * kD);
  const float4* y3 = (const float4*)(ws + oU + (size_t)(b0 + 3) * kD);

  float4 pre[8];
#pragma unroll
  for (int k = 0; k < 8; ++k) pre[k] = Wvv[(size_t)k * kD + t];
  float acc0 = 0.f, acc1 = 0.f, acc2 = 0.f, acc3 = 0.f;
  for (int j0 = 0; j0 < 64; j0 += 8) {
    float4 cur[8];
#pragma unroll
    for (int k = 0; k < 8; ++k) cur[k] = pre[k];
    const int nx = (j0 + 8 < 64) ? (j0 + 8) : 0;
#pragma unroll
    for (int k = 0; k < 8; ++k) pre[k] = Wvv[(size_t)(nx + k) * kD + t];
#pragma unroll
    for (int k = 0; k < 8; ++k) {
      const float4 m = cur[k];
      const float4 a0 = y0[j0 + k];
      const float4 a1 = y1[j0 + k];
      const float4 a2 = y2[j0 + k];
      const float4 a3 = y3[j0 + k];
      acc0 += a0.x * m.x + a0.y * m.y + a0.z * m.z + a0.w * m.w;
      acc1 += a1.x * m.x + a1.y * m.y + a1.z * m.z + a1.w * m.w;
      acc2 += a2.x * m.x + a2.y * m.y + a2.z * m.z + a2.w * m.w;
      acc3 += a3.x * m.x + a3.y * m.y + a3.z * m.z + a3.w * m.w;
    }
  }
  const float bvt = bv[t];
  out[(size_t)(b0 + 0) * kD + t] = acc0 + bvt;
  out[(size_t)(b0 + 1) * kD + t] = acc1 + bvt;
  out[(size_t)(b0 + 2) * kD + t] = acc2 + bvt;
  out[(size_t)(b0 + 3) * kD + t] = acc3 + bvt;
}

extern "C" void kernel_launch(void* const* d_in, const int* in_sizes, int n_in,
                              void* d_out, int out_size, void* d_ws,
                              size_t ws_size, hipStream_t stream) {
  const float* x = (const float*)d_in[0];
  const int* mask = (const int*)d_in[1];
  const float* td = (const float*)d_in[2];
  const float* Wq = (const float*)d_in[3];
  const float* bq = (const float*)d_in[4];
  const float* Wk = (const float*)d_in[5];
  const float* bk = (const float*)d_in[6];
  const float* Wv = (const float*)d_in[7];
  const float* bv = (const float*)d_in[8];
  float* ws = (float*)d_ws;  // ~2.7 MB used
  float* out = (float*)d_out;
  (void)in_sizes; (void)n_in; (void)out_size; (void)ws_size;

  hipLaunchKernelGGL(precomp, dim3(274), dim3(kThr), 0, stream, Wq, bq, Wk, bk,
                     Wv, ws);
  hipLaunchKernelGGL(u_gemm, dim3(kB / 4), dim3(kThr), 0, stream, x, td, ws);
  hipLaunchKernelGGL(attn, dim3(kB), dim3(64), 0, stream, x, mask, td, ws);
  hipLaunchKernelGGL(o_gemm, dim3(kB / 4), dim3(kThr), 0, stream, bv, ws, out);
}